// Round 3
// baseline (825.123 us; speedup 1.0000x reference)
//
#include <hip/hip_runtime.h>
#include <hip/hip_bf16.h>
#include <hip/hip_cooperative_groups.h>

namespace cg = cooperative_groups;

#define D_IN  32
#define D_EF  16
#define D_H   64
#define D_MSG 32
#define D_UP  32

// Max edges held in registers per thread across the cooperative phases.
// ceil(1.6M / (1024*256)) = 7; overflow loop handles any excess (robust to
// smaller grids from the occupancy query).
#define MAXE 7

// NOTE: __builtin_amdgcn_cvt_pkrtz / fdot2 use the __fp16-based vector type;
// _Float16-based ext vectors are treated as incompatible by clang.
typedef __fp16 v2h __attribute__((ext_vector_type(2)));

// bf16 helpers: pack two fp32 -> uint32 (RNE), unpack low/high half
__device__ __forceinline__ unsigned bf16pair(float a, float b) {
    unsigned ua = __float_as_uint(a);
    ua = (ua + 0x7fffu + ((ua >> 16) & 1u)) >> 16;
    unsigned ub = __float_as_uint(b);
    ub = (ub + 0x7fffu + ((ub >> 16) & 1u)) >> 16;
    return ua | (ub << 16);
}
__device__ __forceinline__ float bf_lo(unsigned u) { return __uint_as_float(u << 16); }
__device__ __forceinline__ float bf_hi(unsigned u) { return __uint_as_float(u & 0xffff0000u); }

// ---------------------------------------------------------------------------
// Cooperative fused front-end (single launch, grid-resident):
//   A: W1E pack + node precompute (P1 fp32, P2 bf16) + edge hist where each
//      thread KEEPS (src,dst,rank) in registers.
//   [grid.sync]  B: hierarchical exclusive scan deg -> offs (2 internal syncs)
//   [grid.sync]  C: scatter edges from registers (nontemporal 8B stores).
// Deletes: rank array traffic (12.8 MB), ei re-read (12.8 MB), 4 dispatch
// boundaries vs the previous prep/scan x3/scatter chain.
// ---------------------------------------------------------------------------
__global__ __launch_bounds__(256, 4) void front_kernel(
    const float* __restrict__ x,
    const float* __restrict__ W1m,
    const float* __restrict__ b1m,
    const int*   __restrict__ ei,
    float* __restrict__ P1,
    unsigned short* __restrict__ P2b,
    int* __restrict__ deg,
    int* __restrict__ offs,
    int* __restrict__ bsum,
    int* __restrict__ boffs,
    v2h* __restrict__ W1Ep,
    long long* __restrict__ edges_sorted,
    int* __restrict__ rank_ovf,
    int n_nodes, int n_edges, int NBn)
{
    cg::grid_group grid = cg::this_grid();
    const int t   = threadIdx.x;
    const int tid = blockIdx.x * 256 + t;
    const int nth = gridDim.x * 256;

    __shared__ int sdata[256];

    // ---------- A0: W1E fdot2 pair packing (block 0) ----------
    if (blockIdx.x == 0) {
        const float* W1E = W1m + (size_t)(2 * D_IN) * D_H;
        for (int idx = t; idx < 8 * D_H; idx += 256) {
            int kp = idx >> 6, c = idx & 63;
            W1Ep[idx] = __builtin_amdgcn_cvt_pkrtz(W1E[(2 * kp) * D_H + c],
                                                   W1E[(2 * kp + 1) * D_H + c]);
        }
    }

    // ---------- A1: node precompute (grid-stride; 32-col chunks keep
    //               VGPR <= 128 for the cooperative residency bound) ----------
    for (int i = tid; i < n_nodes; i += nth) {
        float xi[D_IN];
        const float4* xp = (const float4*)(x + (size_t)i * D_IN);
#pragma unroll
        for (int k4 = 0; k4 < D_IN / 4; ++k4) {
            float4 v = xp[k4];
            xi[4 * k4 + 0] = v.x; xi[4 * k4 + 1] = v.y;
            xi[4 * k4 + 2] = v.z; xi[4 * k4 + 3] = v.w;
        }
        // P1 = x @ W1m[0:32] + b1m   (two 32-col chunks)
        for (int half = 0; half < 2; ++half) {
            float acc[32];
#pragma unroll
            for (int j = 0; j < 32; ++j) acc[j] = b1m[half * 32 + j];
            for (int k = 0; k < D_IN; ++k) {
                float xv = xi[k];
                const float* wr = W1m + (size_t)k * D_H + half * 32;
#pragma unroll
                for (int j = 0; j < 32; ++j) acc[j] += xv * wr[j];
            }
            float4* o = (float4*)(P1 + (size_t)i * D_H + half * 32);
#pragma unroll
            for (int j4 = 0; j4 < 8; ++j4)
                o[j4] = make_float4(acc[4 * j4], acc[4 * j4 + 1],
                                    acc[4 * j4 + 2], acc[4 * j4 + 3]);
        }
        // P2b = bf16( x @ W1m[32:64] )   (two 32-col chunks)
        for (int half = 0; half < 2; ++half) {
            float acc[32];
#pragma unroll
            for (int j = 0; j < 32; ++j) acc[j] = 0.0f;
            for (int k = 0; k < D_IN; ++k) {
                float xv = xi[k];
                const float* wr = W1m + (size_t)(k + D_IN) * D_H + half * 32;
#pragma unroll
                for (int j = 0; j < 32; ++j) acc[j] += xv * wr[j];
            }
            uint4* o = (uint4*)(P2b + (size_t)i * D_H + half * 32);
#pragma unroll
            for (int j8 = 0; j8 < 4; ++j8) {
                uint4 q;
                q.x = bf16pair(acc[8 * j8 + 0], acc[8 * j8 + 1]);
                q.y = bf16pair(acc[8 * j8 + 2], acc[8 * j8 + 3]);
                q.z = bf16pair(acc[8 * j8 + 4], acc[8 * j8 + 5]);
                q.w = bf16pair(acc[8 * j8 + 6], acc[8 * j8 + 7]);
                o[j8] = q;
            }
        }
    }

    // ---------- A2: edge hist + rank, held in registers ----------
    int esrc[MAXE], edst[MAXE], ernk[MAXE];
#pragma unroll
    for (int q = 0; q < MAXE; ++q) {
        int e = tid + q * nth;
        esrc[q] = 0; edst[q] = 0; ernk[q] = 0;
        if (e < n_edges) {
            esrc[q] = ei[e];
            edst[q] = ei[n_edges + e];
            ernk[q] = atomicAdd(&deg[edst[q]], 1);
        }
    }
    // overflow (only if grid smaller than expected)
    for (int e = tid + MAXE * nth; e < n_edges; e += nth)
        rank_ovf[e] = atomicAdd(&deg[ei[n_edges + e]], 1);

    grid.sync();

    // ---------- B1: per-chunk inclusive scan -> partial offs + bsum ----------
    {
        int b = blockIdx.x;
        if (b < NBn) {
            int idx = b * 256 + t;
            sdata[t] = (idx < n_nodes) ? deg[idx] : 0;
            __syncthreads();
            for (int off = 1; off < 256; off <<= 1) {
                int u = (t >= off) ? sdata[t - off] : 0;
                __syncthreads();
                sdata[t] += u;
                __syncthreads();
            }
            if (t == 255) bsum[b] = sdata[255];
            if (idx < n_nodes) offs[idx] = (t > 0) ? sdata[t - 1] : 0;
        }
    }
    grid.sync();

    // ---------- B2: scan of block sums (block 0; NBn <= 256) ----------
    if (blockIdx.x == 0) {
        sdata[t] = (t < NBn) ? bsum[t] : 0;
        __syncthreads();
        for (int off = 1; off < 256; off <<= 1) {
            int u = (t >= off) ? sdata[t - off] : 0;
            __syncthreads();
            sdata[t] += u;
            __syncthreads();
        }
        if (t < NBn) boffs[t] = (t > 0) ? sdata[t - 1] : 0;
    }
    grid.sync();

    // ---------- B3: add block base ----------
    {
        int b = blockIdx.x;
        if (b > 0 && b < NBn) {
            int idx = b * 256 + t;
            if (idx < n_nodes) offs[idx] += boffs[b];
        }
    }
    grid.sync();

    // ---------- C: scatter from registers (atomic-free, unique positions) ----
#pragma unroll
    for (int q = 0; q < MAXE; ++q) {
        int e = tid + q * nth;
        if (e < n_edges) {
            int pos = offs[edst[q]] + ernk[q];
            long long v = (long long)((unsigned long long)(unsigned)esrc[q] << 32)
                        | (unsigned long long)(unsigned)e;
            __builtin_nontemporal_store(v, &edges_sorted[pos]);
        }
    }
    for (int e = tid + MAXE * nth; e < n_edges; e += nth) {
        int s = ei[e];
        int d = ei[n_edges + e];
        int pos = offs[d] + rank_ovf[e];
        long long v = (long long)((unsigned long long)(unsigned)s << 32)
                    | (unsigned long long)(unsigned)e;
        edges_sorted[pos] = v;
    }
}

// ---------------------------------------------------------------------------
// Gather-aggregate. Layer-2 hoisted (hsum = sum relu(h); W2 applied per-node
// in node_upd). Comp-split across the 4 waves (wave owns 16 comps, hacc=16
// VGPRs, weights stay SGPR-fed). NEW: paired-edge unroll-2 — slots i and i+16
// processed per iteration with all loads issued together, halving the number
// of dependent es->ef/P2b load chains (trip count is only ~2 at deg~32).
// ---------------------------------------------------------------------------
__global__ __launch_bounds__(256) void gather_kernel(
    const float* __restrict__ ef,
    const v2h*  __restrict__ W1Ep,
    const float* __restrict__ P1,
    const unsigned short* __restrict__ P2b,
    const int*  __restrict__ deg,
    const int*  __restrict__ offs,
    const long long* __restrict__ edges_sorted,
    float* __restrict__ hagg,
    int n_nodes)
{
    const int lane = threadIdx.x & 63;
    const int cq   = __builtin_amdgcn_readfirstlane((int)(threadIdx.x >> 6));
    const int g    = lane >> 4;        // node sub-index in block
    const int t    = lane & 15;        // edge slot
    const int n    = blockIdx.x * 4 + g;
    if (n >= n_nodes) return;

    const int start = offs[n];
    const int end   = start + deg[n];

    float p1q[16];
    {
        const float4* pp = (const float4*)(P1 + (size_t)n * D_H + cq * 16);
#pragma unroll
        for (int q = 0; q < 4; ++q) {
            float4 v = pp[q];
            p1q[4 * q + 0] = v.x; p1q[4 * q + 1] = v.y;
            p1q[4 * q + 2] = v.z; p1q[4 * q + 3] = v.w;
        }
    }

    const v2h* wbase = W1Ep + 16 * cq;   // wave-uniform -> scalar loads

    float hacc[16];
#pragma unroll
    for (int c = 0; c < 16; ++c) hacc[c] = 0.0f;

    for (int i = start + t; i < end; i += 32) {
        const int  iB = i + 16;
        const bool hB = iB < end;
        long long eA = edges_sorted[i];
        long long eB = edges_sorted[hB ? iB : i];   // clamped -> always valid
        int exA = (int)eA, syA = (int)(eA >> 32);
        int exB = (int)eB, syB = (int)(eB >> 32);

        const float4* fpA = (const float4*)(ef + (size_t)(unsigned)exA * D_EF);
        const float4* fpB = (const float4*)(ef + (size_t)(unsigned)exB * D_EF);
        float4 A0 = fpA[0], A1 = fpA[1], A2 = fpA[2], A3 = fpA[3];
        float4 B0 = fpB[0], B1 = fpB[1], B2 = fpB[2], B3 = fpB[3];
        const uint4* pA = (const uint4*)(P2b + (size_t)(unsigned)syA * D_H + cq * 16);
        const uint4* pB = (const uint4*)(P2b + (size_t)(unsigned)syB * D_H + cq * 16);
        uint4 a0 = pA[0], a1 = pA[1];
        uint4 b0 = pB[0], b1 = pB[1];

        v2h ehA[8], ehB[8];
        ehA[0] = __builtin_amdgcn_cvt_pkrtz(A0.x, A0.y);
        ehA[1] = __builtin_amdgcn_cvt_pkrtz(A0.z, A0.w);
        ehA[2] = __builtin_amdgcn_cvt_pkrtz(A1.x, A1.y);
        ehA[3] = __builtin_amdgcn_cvt_pkrtz(A1.z, A1.w);
        ehA[4] = __builtin_amdgcn_cvt_pkrtz(A2.x, A2.y);
        ehA[5] = __builtin_amdgcn_cvt_pkrtz(A2.z, A2.w);
        ehA[6] = __builtin_amdgcn_cvt_pkrtz(A3.x, A3.y);
        ehA[7] = __builtin_amdgcn_cvt_pkrtz(A3.z, A3.w);
        ehB[0] = __builtin_amdgcn_cvt_pkrtz(B0.x, B0.y);
        ehB[1] = __builtin_amdgcn_cvt_pkrtz(B0.z, B0.w);
        ehB[2] = __builtin_amdgcn_cvt_pkrtz(B1.x, B1.y);
        ehB[3] = __builtin_amdgcn_cvt_pkrtz(B1.z, B1.w);
        ehB[4] = __builtin_amdgcn_cvt_pkrtz(B2.x, B2.y);
        ehB[5] = __builtin_amdgcn_cvt_pkrtz(B2.z, B2.w);
        ehB[6] = __builtin_amdgcn_cvt_pkrtz(B3.x, B3.y);
        ehB[7] = __builtin_amdgcn_cvt_pkrtz(B3.z, B3.w);

        // ---- edge A ----
#pragma unroll
        for (int jj = 0; jj < 2; ++jj) {
            uint4 bb = jj ? a1 : a0;
            float h[8];
            h[0] = p1q[8 * jj + 0] + bf_lo(bb.x);
            h[1] = p1q[8 * jj + 1] + bf_hi(bb.x);
            h[2] = p1q[8 * jj + 2] + bf_lo(bb.y);
            h[3] = p1q[8 * jj + 3] + bf_hi(bb.y);
            h[4] = p1q[8 * jj + 4] + bf_lo(bb.z);
            h[5] = p1q[8 * jj + 5] + bf_hi(bb.z);
            h[6] = p1q[8 * jj + 6] + bf_lo(bb.w);
            h[7] = p1q[8 * jj + 7] + bf_hi(bb.w);
#pragma unroll
            for (int kp = 0; kp < D_EF / 2; ++kp) {
                const v2h* wr = wbase + kp * D_H + 8 * jj;
#pragma unroll
                for (int c8 = 0; c8 < 8; ++c8)
                    h[c8] = __builtin_amdgcn_fdot2(ehA[kp], wr[c8], h[c8], false);
            }
#pragma unroll
            for (int c8 = 0; c8 < 8; ++c8) {
                float r = h[c8] > 0.0f ? h[c8] : 0.0f;
                hacc[8 * jj + c8] += r;
            }
        }
        // ---- edge B (accumulate masked) ----
#pragma unroll
        for (int jj = 0; jj < 2; ++jj) {
            uint4 bb = jj ? b1 : b0;
            float h[8];
            h[0] = p1q[8 * jj + 0] + bf_lo(bb.x);
            h[1] = p1q[8 * jj + 1] + bf_hi(bb.x);
            h[2] = p1q[8 * jj + 2] + bf_lo(bb.y);
            h[3] = p1q[8 * jj + 3] + bf_hi(bb.y);
            h[4] = p1q[8 * jj + 4] + bf_lo(bb.z);
            h[5] = p1q[8 * jj + 5] + bf_hi(bb.z);
            h[6] = p1q[8 * jj + 6] + bf_lo(bb.w);
            h[7] = p1q[8 * jj + 7] + bf_hi(bb.w);
#pragma unroll
            for (int kp = 0; kp < D_EF / 2; ++kp) {
                const v2h* wr = wbase + kp * D_H + 8 * jj;
#pragma unroll
                for (int c8 = 0; c8 < 8; ++c8)
                    h[c8] = __builtin_amdgcn_fdot2(ehB[kp], wr[c8], h[c8], false);
            }
#pragma unroll
            for (int c8 = 0; c8 < 8; ++c8) {
                float r = h[c8] > 0.0f ? h[c8] : 0.0f;
                hacc[8 * jj + c8] += hB ? r : 0.0f;
            }
        }
    }

    // ---- 4-stage butterfly compaction across the node's 16 lanes ----
    float r1[8];
    {
        const bool up = (t & 8) != 0;
#pragma unroll
        for (int c = 0; c < 8; ++c) {
            float lo = hacc[c]     + __shfl_xor(hacc[c],     8, 16);
            float hi = hacc[c + 8] + __shfl_xor(hacc[c + 8], 8, 16);
            r1[c] = up ? hi : lo;
        }
    }
    float r2[4];
    {
        const bool up = (t & 4) != 0;
#pragma unroll
        for (int c = 0; c < 4; ++c) {
            float lo = r1[c]     + __shfl_xor(r1[c],     4, 16);
            float hi = r1[c + 4] + __shfl_xor(r1[c + 4], 4, 16);
            r2[c] = up ? hi : lo;
        }
    }
    float r3[2];
    {
        const bool up = (t & 2) != 0;
#pragma unroll
        for (int c = 0; c < 2; ++c) {
            float lo = r2[c]     + __shfl_xor(r2[c],     2, 16);
            float hi = r2[c + 2] + __shfl_xor(r2[c + 2], 2, 16);
            r3[c] = up ? hi : lo;
        }
    }
    float r4;
    {
        const bool up = (t & 1) != 0;
        float lo = r3[0] + __shfl_xor(r3[0], 1, 16);
        float hi = r3[1] + __shfl_xor(r3[1], 1, 16);
        r4 = up ? hi : lo;
    }

    hagg[(size_t)n * D_H + cq * 16 + t] = r4;
}

// ---------------------------------------------------------------------------
// Per-node update MLP. Absorbs the hoisted layer-2:
//   aggm = hsum @ W2m + deg*b2m
//   out  = relu([x, aggm] @ W1u + b1u) @ W2u + b2u
// ---------------------------------------------------------------------------
__global__ __launch_bounds__(256) void node_upd_kernel(
    const float* __restrict__ x,
    const float* __restrict__ hagg,
    const int*   __restrict__ deg,
    const float* __restrict__ b2m,
    const float* __restrict__ W2m,
    const float* __restrict__ W1u,
    const float* __restrict__ b1u,
    const float* __restrict__ W2u,
    const float* __restrict__ b2u,
    float* __restrict__ out,
    int n_nodes)
{
    int i = blockIdx.x * blockDim.x + threadIdx.x;
    if (i >= n_nodes) return;

    float in[D_IN + D_MSG];
    const float4* xp = (const float4*)(x + (size_t)i * D_IN);
#pragma unroll
    for (int k4 = 0; k4 < D_IN / 4; ++k4) {
        float4 v = xp[k4];
        in[4 * k4 + 0] = v.x; in[4 * k4 + 1] = v.y;
        in[4 * k4 + 2] = v.z; in[4 * k4 + 3] = v.w;
    }

    float dc = (float)deg[i];
#pragma unroll
    for (int m = 0; m < D_MSG; ++m) in[D_IN + m] = dc * b2m[m];

    const float4* hp = (const float4*)(hagg + (size_t)i * D_H);
    for (int j4 = 0; j4 < D_H / 4; ++j4) {
        float4 v = hp[j4];
        const float* w0 = W2m + (size_t)(4 * j4 + 0) * D_MSG;
        const float* w1 = W2m + (size_t)(4 * j4 + 1) * D_MSG;
        const float* w2 = W2m + (size_t)(4 * j4 + 2) * D_MSG;
        const float* w3 = W2m + (size_t)(4 * j4 + 3) * D_MSG;
#pragma unroll
        for (int m = 0; m < D_MSG; ++m)
            in[D_IN + m] += v.x * w0[m] + v.y * w1[m] + v.z * w2[m] + v.w * w3[m];
    }

    float h[D_H];
#pragma unroll
    for (int j = 0; j < D_H; ++j) h[j] = b1u[j];
    for (int k = 0; k < D_IN + D_MSG; ++k) {
        float v = in[k];
        const float* wr = W1u + (size_t)k * D_H;
#pragma unroll
        for (int j = 0; j < D_H; ++j) h[j] += v * wr[j];
    }

    float o[D_UP];
#pragma unroll
    for (int m = 0; m < D_UP; ++m) o[m] = b2u[m];
    for (int j = 0; j < D_H; ++j) {
        float r = h[j] > 0.0f ? h[j] : 0.0f;
        const float* wr = W2u + (size_t)j * D_UP;
#pragma unroll
        for (int m = 0; m < D_UP; ++m) o[m] += r * wr[m];
    }

    float4* op = (float4*)(out + (size_t)i * D_UP);
#pragma unroll
    for (int m4 = 0; m4 < D_UP / 4; ++m4)
        op[m4] = make_float4(o[4 * m4], o[4 * m4 + 1], o[4 * m4 + 2], o[4 * m4 + 3]);
}

extern "C" void kernel_launch(void* const* d_in, const int* in_sizes, int n_in,
                              void* d_out, int out_size, void* d_ws, size_t ws_size,
                              hipStream_t stream) {
    const float* x    = (const float*)d_in[0];
    // d_in[1] = degrees — unused by the reference computation
    const float* ef   = (const float*)d_in[2];
    const float* W1m  = (const float*)d_in[3];
    const float* b1m  = (const float*)d_in[4];
    const float* W2m  = (const float*)d_in[5];
    const float* b2m  = (const float*)d_in[6];
    const float* W1u  = (const float*)d_in[7];
    const float* b1u  = (const float*)d_in[8];
    const float* W2u  = (const float*)d_in[9];
    const float* b2u  = (const float*)d_in[10];
    const int*   ei   = (const int*)d_in[11];

    const int n_nodes = in_sizes[0] / D_IN;      // 50000
    const int n_edges = in_sizes[11] / 2;        // 1600000

    float* out = (float*)d_out;

    const int NBn = (n_nodes + 255) / 256;       // 196 (<=256 req'd for scan)

    // Workspace layout (~45.2 MB):
    //   P1           : n_nodes * D_H    f    (12.8 MB)
    //   P2b          : n_nodes * D_H    u16  (6.4 MB)
    //   edges_sorted : n_edges          ll   (12.8 MB)
    //   deg/offs     : n_nodes          i
    //   bsum/boffs   : NBn              i
    //   W1Ep         : 8*64   v2h (2 KB)
    //   tail (ALIASED by lifetime):
    //     rank_ovf : n_edges i     (live within front only; normally untouched)
    //     hagg     : n_nodes*D_H f (live gather -> node_upd)
    float*          P1  = (float*)d_ws;
    unsigned short* P2b = (unsigned short*)(P1 + (size_t)n_nodes * D_H);
    long long* edges_sorted = (long long*)(P2b + (size_t)n_nodes * D_H);
    int* deg    = (int*)(edges_sorted + n_edges);
    int* offs   = deg    + n_nodes;
    int* bsum   = offs   + n_nodes;
    int* boffs  = bsum   + 256;
    v2h* W1Ep   = (v2h*)(boffs + 256);
    int* rank_ovf = (int*)(W1Ep + 8 * D_H);
    float* hagg   = (float*)rank_ovf;            // alias (disjoint lifetime)

    // Cooperative grid size: max co-resident blocks (cached; host-only query,
    // graph-capture safe). launch_bounds(256,4) targets >=4 blocks/CU -> 1024.
    static int s_G = 0;
    if (s_G == 0) {
        hipDeviceProp_t prop;
        hipGetDeviceProperties(&prop, 0);
        int nbpc = 0;
        hipOccupancyMaxActiveBlocksPerMultiprocessor(&nbpc, front_kernel, 256, 0);
        if (nbpc < 1) nbpc = 1;
        if (nbpc > 4) nbpc = 4;
        int g = prop.multiProcessorCount * nbpc;
        if (g > 2048) g = 2048;
        if (g < NBn) g = NBn;                    // scan mapping requirement
        s_G = g;
    }

    hipMemsetAsync(deg, 0, (size_t)n_nodes * sizeof(int), stream);

    {
        int ne = n_edges, nn = n_nodes, nb = NBn;
        void* args[] = {
            (void*)&x, (void*)&W1m, (void*)&b1m, (void*)&ei,
            (void*)&P1, (void*)&P2b, (void*)&deg, (void*)&offs,
            (void*)&bsum, (void*)&boffs, (void*)&W1Ep, (void*)&edges_sorted,
            (void*)&rank_ovf, (void*)&nn, (void*)&ne, (void*)&nb
        };
        hipLaunchCooperativeKernel(front_kernel, dim3(s_G), dim3(256),
                                   args, 0, stream);
    }

    {
        int grid = (n_nodes + 3) / 4;   // 4 nodes/block, 4 waves = comp quarters
        gather_kernel<<<grid, 256, 0, stream>>>(ef, W1Ep, P1, P2b,
                                                deg, offs, edges_sorted, hagg,
                                                n_nodes);
    }
    node_upd_kernel<<<NBn, 256, 0, stream>>>(x, hagg, deg, b2m, W2m,
                                             W1u, b1u, W2u, b2u, out, n_nodes);
}

// Round 4
// 474.780 us; speedup vs baseline: 1.7379x; 1.7379x over previous
//
#include <hip/hip_runtime.h>
#include <hip/hip_bf16.h>

#define D_IN  32
#define D_EF  16
#define D_H   64
#define D_MSG 32
#define D_UP  32

// NOTE: __builtin_amdgcn_cvt_pkrtz / fdot2 use the __fp16-based vector type;
// _Float16-based ext vectors are treated as incompatible by clang.
typedef __fp16 v2h __attribute__((ext_vector_type(2)));

// bf16 helpers: pack two fp32 -> uint32 (RNE), unpack low/high half
__device__ __forceinline__ unsigned bf16pair(float a, float b) {
    unsigned ua = __float_as_uint(a);
    ua = (ua + 0x7fffu + ((ua >> 16) & 1u)) >> 16;
    unsigned ub = __float_as_uint(b);
    ub = (ub + 0x7fffu + ((ub >> 16) & 1u)) >> 16;
    return ua | (ub << 16);
}
__device__ __forceinline__ float bf_lo(unsigned u) { return __uint_as_float(u << 16); }
__device__ __forceinline__ float bf_hi(unsigned u) { return __uint_as_float(u & 0xffff0000u); }

// ---------------------------------------------------------------------------
// Fused front-end (independent stages dispatched by block range):
//   blocks [0, NBn)            : node_pre  (P1 fp32, P2 bf16 precompute)
//   blocks [NBn, NBn+NBe)      : hist + rank capture:
//                                  rank[e] = atomicAdd(&deg[dst[e]], 1)
//   block  NBn+NBe             : W1E pair-packing for fdot2
// ---------------------------------------------------------------------------
__global__ __launch_bounds__(256) void prep_kernel(
    const float* __restrict__ x,
    const float* __restrict__ W1m,
    const float* __restrict__ b1m,
    const int*   __restrict__ ei,
    float* __restrict__ P1,
    unsigned short* __restrict__ P2b,
    int* __restrict__ deg,
    int* __restrict__ rank,
    v2h* __restrict__ W1Ep,
    int n_nodes, int n_edges, int NBn, int NBe)
{
    int b = blockIdx.x;

    if (b < NBn) {
        // ---------------- node_pre ----------------
        int i = b * 256 + threadIdx.x;
        if (i >= n_nodes) return;

        float xi[D_IN];
        const float4* xp = (const float4*)(x + (size_t)i * D_IN);
#pragma unroll
        for (int k4 = 0; k4 < D_IN / 4; ++k4) {
            float4 v = xp[k4];
            xi[4 * k4 + 0] = v.x; xi[4 * k4 + 1] = v.y;
            xi[4 * k4 + 2] = v.z; xi[4 * k4 + 3] = v.w;
        }
        {
            float acc[D_H];
#pragma unroll
            for (int j = 0; j < D_H; ++j) acc[j] = b1m[j];
            for (int k = 0; k < D_IN; ++k) {
                float xv = xi[k];
                const float* wr = W1m + (size_t)k * D_H;
#pragma unroll
                for (int j = 0; j < D_H; ++j) acc[j] += xv * wr[j];
            }
            float4* o = (float4*)(P1 + (size_t)i * D_H);
#pragma unroll
            for (int j4 = 0; j4 < D_H / 4; ++j4)
                o[j4] = make_float4(acc[4 * j4], acc[4 * j4 + 1],
                                    acc[4 * j4 + 2], acc[4 * j4 + 3]);
        }
        {
            float acc[D_H];
#pragma unroll
            for (int j = 0; j < D_H; ++j) acc[j] = 0.0f;
            for (int k = 0; k < D_IN; ++k) {
                float xv = xi[k];
                const float* wr = W1m + (size_t)(k + D_IN) * D_H;
#pragma unroll
                for (int j = 0; j < D_H; ++j) acc[j] += xv * wr[j];
            }
            uint4* o = (uint4*)(P2b + (size_t)i * D_H);
#pragma unroll
            for (int j8 = 0; j8 < D_H / 8; ++j8) {
                uint4 q;
                q.x = bf16pair(acc[8 * j8 + 0], acc[8 * j8 + 1]);
                q.y = bf16pair(acc[8 * j8 + 2], acc[8 * j8 + 3]);
                q.z = bf16pair(acc[8 * j8 + 4], acc[8 * j8 + 5]);
                q.w = bf16pair(acc[8 * j8 + 6], acc[8 * j8 + 7]);
                o[j8] = q;
            }
        }
    } else if (b < NBn + NBe) {
        // ---------------- hist + rank ----------------
        int e = (b - NBn) * 256 + threadIdx.x;
        if (e < n_edges)
            rank[e] = atomicAdd(&deg[ei[n_edges + e]], 1);
    } else {
        // ---------------- pack W1E for fdot2 ----------------
        int t = threadIdx.x;
        const float* W1E = W1m + (size_t)(2 * D_IN) * D_H;
        for (int idx = t; idx < 8 * D_H; idx += 256) {
            int kp = idx >> 6, c = idx & 63;
            W1Ep[idx] = __builtin_amdgcn_cvt_pkrtz(W1E[(2 * kp) * D_H + c],
                                                   W1E[(2 * kp + 1) * D_H + c]);
        }
    }
}

// ---------------------------------------------------------------------------
// 3-phase multi-block exclusive scan of deg -> offs
// ---------------------------------------------------------------------------
__global__ __launch_bounds__(256) void scan_partials_kernel(
    const int* __restrict__ deg, int* __restrict__ bsum, int n_nodes)
{
    int idx = blockIdx.x * 256 + threadIdx.x;
    int v = (idx < n_nodes) ? deg[idx] : 0;
#pragma unroll
    for (int o = 1; o < 64; o <<= 1) v += __shfl_xor(v, o, 64);
    __shared__ int ws[4];
    int lane = threadIdx.x & 63, w = threadIdx.x >> 6;
    if (lane == 0) ws[w] = v;
    __syncthreads();
    if (threadIdx.x == 0) bsum[blockIdx.x] = ws[0] + ws[1] + ws[2] + ws[3];
}

__global__ __launch_bounds__(256) void scan_blockoffs_kernel(
    const int* __restrict__ bsum, int* __restrict__ boffs, int nb)
{
    __shared__ int sdata[256];
    int t = threadIdx.x;
    sdata[t] = (t < nb) ? bsum[t] : 0;
    __syncthreads();
    for (int off = 1; off < 256; off <<= 1) {
        int u = (t >= off) ? sdata[t - off] : 0;
        __syncthreads();
        sdata[t] += u;
        __syncthreads();
    }
    if (t < nb) boffs[t] = (t > 0) ? sdata[t - 1] : 0;
}

__global__ __launch_bounds__(256) void scan_final_kernel(
    const int* __restrict__ deg, const int* __restrict__ boffs,
    int* __restrict__ offs, int n_nodes)
{
    __shared__ int sdata[256];
    int t = threadIdx.x;
    int idx = blockIdx.x * 256 + t;
    sdata[t] = (idx < n_nodes) ? deg[idx] : 0;
    __syncthreads();
    for (int off = 1; off < 256; off <<= 1) {
        int u = (t >= off) ? sdata[t - off] : 0;
        __syncthreads();
        sdata[t] += u;
        __syncthreads();
    }
    int excl = boffs[blockIdx.x] + ((t > 0) ? sdata[t - 1] : 0);
    if (idx < n_nodes) offs[idx] = excl;
}

// ---------------------------------------------------------------------------
// Atomic-free scatter: pos = offs[dst] + rank[e]  (unique by construction).
// Packs (src << 32) | e so gather never touches ei. REGULAR stores: the
// scattered 8B writes MUST flow through L2 so same-line writes (a node's
// bucket is contiguous) merge before eviction — nt stores here caused 13x
// write amplification (round-3 lesson). nt LOADS are fine: ei/rank are
// streamed exactly once, so bypassing cache keeps L2 for offs.
// ---------------------------------------------------------------------------
__global__ __launch_bounds__(256) void scatter_kernel(
    const int* __restrict__ ei,
    const int* __restrict__ rank,
    const int* __restrict__ offs,
    long long* __restrict__ edges_sorted,
    int n_edges)
{
    int e = blockIdx.x * blockDim.x + threadIdx.x;
    if (e < n_edges) {
        int s = __builtin_nontemporal_load(&ei[e]);
        int d = __builtin_nontemporal_load(&ei[n_edges + e]);
        int r = __builtin_nontemporal_load(&rank[e]);
        int pos = offs[d] + r;
        long long v = (long long)((unsigned long long)(unsigned)s << 32)
                    | (unsigned long long)(unsigned)e;
        edges_sorted[pos] = v;
    }
}

// ---------------------------------------------------------------------------
// Gather-aggregate. Layer-2 hoisted (hsum = sum relu(h); W2 applied per-node
// in node_upd). Comp-split across the 4 waves (wave owns 16 comps, hacc=16
// VGPRs, W1E weights stay SGPR-fed). Paired-edge unroll-2: slots i and i+16
// per iteration with all loads issued together, halving the dependent
// es->ef/P2b load chains (trip count ~2 at deg~32 -> ~1).
// launch_bounds(256,4) caps VGPR at 128 (occupancy floor; round-1 lesson).
// ---------------------------------------------------------------------------
__global__ __launch_bounds__(256, 4) void gather_kernel(
    const float* __restrict__ ef,
    const v2h*  __restrict__ W1Ep,
    const float* __restrict__ P1,
    const unsigned short* __restrict__ P2b,
    const int*  __restrict__ deg,
    const int*  __restrict__ offs,
    const long long* __restrict__ edges_sorted,
    float* __restrict__ hagg,
    int n_nodes)
{
    const int lane = threadIdx.x & 63;
    const int cq   = __builtin_amdgcn_readfirstlane((int)(threadIdx.x >> 6));
    const int g    = lane >> 4;        // node sub-index in block
    const int t    = lane & 15;        // edge slot
    const int n    = blockIdx.x * 4 + g;
    if (n >= n_nodes) return;

    const int start = offs[n];
    const int end   = start + deg[n];

    float p1q[16];
    {
        const float4* pp = (const float4*)(P1 + (size_t)n * D_H + cq * 16);
#pragma unroll
        for (int q = 0; q < 4; ++q) {
            float4 v = pp[q];
            p1q[4 * q + 0] = v.x; p1q[4 * q + 1] = v.y;
            p1q[4 * q + 2] = v.z; p1q[4 * q + 3] = v.w;
        }
    }

    const v2h* wbase = W1Ep + 16 * cq;   // wave-uniform -> scalar loads

    float hacc[16];
#pragma unroll
    for (int c = 0; c < 16; ++c) hacc[c] = 0.0f;

    for (int i = start + t; i < end; i += 32) {
        const int  iB = i + 16;
        const bool hB = iB < end;
        long long eA = __builtin_nontemporal_load(&edges_sorted[i]);
        long long eB = __builtin_nontemporal_load(&edges_sorted[hB ? iB : i]);
        int exA = (int)eA, syA = (int)(eA >> 32);
        int exB = (int)eB, syB = (int)(eB >> 32);

        const float4* fpA = (const float4*)(ef + (size_t)(unsigned)exA * D_EF);
        const float4* fpB = (const float4*)(ef + (size_t)(unsigned)exB * D_EF);
        float4 A0 = fpA[0], A1 = fpA[1], A2 = fpA[2], A3 = fpA[3];
        float4 B0 = fpB[0], B1 = fpB[1], B2 = fpB[2], B3 = fpB[3];
        const uint4* pA = (const uint4*)(P2b + (size_t)(unsigned)syA * D_H + cq * 16);
        const uint4* pB = (const uint4*)(P2b + (size_t)(unsigned)syB * D_H + cq * 16);
        uint4 a0 = pA[0], a1 = pA[1];
        uint4 b0 = pB[0], b1 = pB[1];

        v2h ehA[8], ehB[8];
        ehA[0] = __builtin_amdgcn_cvt_pkrtz(A0.x, A0.y);
        ehA[1] = __builtin_amdgcn_cvt_pkrtz(A0.z, A0.w);
        ehA[2] = __builtin_amdgcn_cvt_pkrtz(A1.x, A1.y);
        ehA[3] = __builtin_amdgcn_cvt_pkrtz(A1.z, A1.w);
        ehA[4] = __builtin_amdgcn_cvt_pkrtz(A2.x, A2.y);
        ehA[5] = __builtin_amdgcn_cvt_pkrtz(A2.z, A2.w);
        ehA[6] = __builtin_amdgcn_cvt_pkrtz(A3.x, A3.y);
        ehA[7] = __builtin_amdgcn_cvt_pkrtz(A3.z, A3.w);
        ehB[0] = __builtin_amdgcn_cvt_pkrtz(B0.x, B0.y);
        ehB[1] = __builtin_amdgcn_cvt_pkrtz(B0.z, B0.w);
        ehB[2] = __builtin_amdgcn_cvt_pkrtz(B1.x, B1.y);
        ehB[3] = __builtin_amdgcn_cvt_pkrtz(B1.z, B1.w);
        ehB[4] = __builtin_amdgcn_cvt_pkrtz(B2.x, B2.y);
        ehB[5] = __builtin_amdgcn_cvt_pkrtz(B2.z, B2.w);
        ehB[6] = __builtin_amdgcn_cvt_pkrtz(B3.x, B3.y);
        ehB[7] = __builtin_amdgcn_cvt_pkrtz(B3.z, B3.w);

        // ---- edge A ----
#pragma unroll
        for (int jj = 0; jj < 2; ++jj) {
            uint4 bb = jj ? a1 : a0;
            float h[8];
            h[0] = p1q[8 * jj + 0] + bf_lo(bb.x);
            h[1] = p1q[8 * jj + 1] + bf_hi(bb.x);
            h[2] = p1q[8 * jj + 2] + bf_lo(bb.y);
            h[3] = p1q[8 * jj + 3] + bf_hi(bb.y);
            h[4] = p1q[8 * jj + 4] + bf_lo(bb.z);
            h[5] = p1q[8 * jj + 5] + bf_hi(bb.z);
            h[6] = p1q[8 * jj + 6] + bf_lo(bb.w);
            h[7] = p1q[8 * jj + 7] + bf_hi(bb.w);
#pragma unroll
            for (int kp = 0; kp < D_EF / 2; ++kp) {
                const v2h* wr = wbase + kp * D_H + 8 * jj;
#pragma unroll
                for (int c8 = 0; c8 < 8; ++c8)
                    h[c8] = __builtin_amdgcn_fdot2(ehA[kp], wr[c8], h[c8], false);
            }
#pragma unroll
            for (int c8 = 0; c8 < 8; ++c8) {
                float r = h[c8] > 0.0f ? h[c8] : 0.0f;
                hacc[8 * jj + c8] += r;
            }
        }
        // ---- edge B (accumulate masked) ----
#pragma unroll
        for (int jj = 0; jj < 2; ++jj) {
            uint4 bb = jj ? b1 : b0;
            float h[8];
            h[0] = p1q[8 * jj + 0] + bf_lo(bb.x);
            h[1] = p1q[8 * jj + 1] + bf_hi(bb.x);
            h[2] = p1q[8 * jj + 2] + bf_lo(bb.y);
            h[3] = p1q[8 * jj + 3] + bf_hi(bb.y);
            h[4] = p1q[8 * jj + 4] + bf_lo(bb.z);
            h[5] = p1q[8 * jj + 5] + bf_hi(bb.z);
            h[6] = p1q[8 * jj + 6] + bf_lo(bb.w);
            h[7] = p1q[8 * jj + 7] + bf_hi(bb.w);
#pragma unroll
            for (int kp = 0; kp < D_EF / 2; ++kp) {
                const v2h* wr = wbase + kp * D_H + 8 * jj;
#pragma unroll
                for (int c8 = 0; c8 < 8; ++c8)
                    h[c8] = __builtin_amdgcn_fdot2(ehB[kp], wr[c8], h[c8], false);
            }
#pragma unroll
            for (int c8 = 0; c8 < 8; ++c8) {
                float r = h[c8] > 0.0f ? h[c8] : 0.0f;
                hacc[8 * jj + c8] += hB ? r : 0.0f;
            }
        }
    }

    // ---- 4-stage butterfly compaction across the node's 16 lanes ----
    float r1[8];
    {
        const bool up = (t & 8) != 0;
#pragma unroll
        for (int c = 0; c < 8; ++c) {
            float lo = hacc[c]     + __shfl_xor(hacc[c],     8, 16);
            float hi = hacc[c + 8] + __shfl_xor(hacc[c + 8], 8, 16);
            r1[c] = up ? hi : lo;
        }
    }
    float r2[4];
    {
        const bool up = (t & 4) != 0;
#pragma unroll
        for (int c = 0; c < 4; ++c) {
            float lo = r1[c]     + __shfl_xor(r1[c],     4, 16);
            float hi = r1[c + 4] + __shfl_xor(r1[c + 4], 4, 16);
            r2[c] = up ? hi : lo;
        }
    }
    float r3[2];
    {
        const bool up = (t & 2) != 0;
#pragma unroll
        for (int c = 0; c < 2; ++c) {
            float lo = r2[c]     + __shfl_xor(r2[c],     2, 16);
            float hi = r2[c + 2] + __shfl_xor(r2[c + 2], 2, 16);
            r3[c] = up ? hi : lo;
        }
    }
    float r4;
    {
        const bool up = (t & 1) != 0;
        float lo = r3[0] + __shfl_xor(r3[0], 1, 16);
        float hi = r3[1] + __shfl_xor(r3[1], 1, 16);
        r4 = up ? hi : lo;
    }

    hagg[(size_t)n * D_H + cq * 16 + t] = r4;
}

// ---------------------------------------------------------------------------
// Per-node update MLP. Absorbs the hoisted layer-2:
//   aggm = hsum @ W2m + deg*b2m
//   out  = relu([x, aggm] @ W1u + b1u) @ W2u + b2u
// ---------------------------------------------------------------------------
__global__ __launch_bounds__(256) void node_upd_kernel(
    const float* __restrict__ x,
    const float* __restrict__ hagg,
    const int*   __restrict__ deg,
    const float* __restrict__ b2m,
    const float* __restrict__ W2m,
    const float* __restrict__ W1u,
    const float* __restrict__ b1u,
    const float* __restrict__ W2u,
    const float* __restrict__ b2u,
    float* __restrict__ out,
    int n_nodes)
{
    int i = blockIdx.x * blockDim.x + threadIdx.x;
    if (i >= n_nodes) return;

    float in[D_IN + D_MSG];
    const float4* xp = (const float4*)(x + (size_t)i * D_IN);
#pragma unroll
    for (int k4 = 0; k4 < D_IN / 4; ++k4) {
        float4 v = xp[k4];
        in[4 * k4 + 0] = v.x; in[4 * k4 + 1] = v.y;
        in[4 * k4 + 2] = v.z; in[4 * k4 + 3] = v.w;
    }

    float dc = (float)deg[i];
#pragma unroll
    for (int m = 0; m < D_MSG; ++m) in[D_IN + m] = dc * b2m[m];

    const float4* hp = (const float4*)(hagg + (size_t)i * D_H);
    for (int j4 = 0; j4 < D_H / 4; ++j4) {
        float4 v = hp[j4];
        const float* w0 = W2m + (size_t)(4 * j4 + 0) * D_MSG;
        const float* w1 = W2m + (size_t)(4 * j4 + 1) * D_MSG;
        const float* w2 = W2m + (size_t)(4 * j4 + 2) * D_MSG;
        const float* w3 = W2m + (size_t)(4 * j4 + 3) * D_MSG;
#pragma unroll
        for (int m = 0; m < D_MSG; ++m)
            in[D_IN + m] += v.x * w0[m] + v.y * w1[m] + v.z * w2[m] + v.w * w3[m];
    }

    float h[D_H];
#pragma unroll
    for (int j = 0; j < D_H; ++j) h[j] = b1u[j];
    for (int k = 0; k < D_IN + D_MSG; ++k) {
        float v = in[k];
        const float* wr = W1u + (size_t)k * D_H;
#pragma unroll
        for (int j = 0; j < D_H; ++j) h[j] += v * wr[j];
    }

    float o[D_UP];
#pragma unroll
    for (int m = 0; m < D_UP; ++m) o[m] = b2u[m];
    for (int j = 0; j < D_H; ++j) {
        float r = h[j] > 0.0f ? h[j] : 0.0f;
        const float* wr = W2u + (size_t)j * D_UP;
#pragma unroll
        for (int m = 0; m < D_UP; ++m) o[m] += r * wr[m];
    }

    float4* op = (float4*)(out + (size_t)i * D_UP);
#pragma unroll
    for (int m4 = 0; m4 < D_UP / 4; ++m4)
        op[m4] = make_float4(o[4 * m4], o[4 * m4 + 1], o[4 * m4 + 2], o[4 * m4 + 3]);
}

extern "C" void kernel_launch(void* const* d_in, const int* in_sizes, int n_in,
                              void* d_out, int out_size, void* d_ws, size_t ws_size,
                              hipStream_t stream) {
    const float* x    = (const float*)d_in[0];
    // d_in[1] = degrees — unused by the reference computation
    const float* ef   = (const float*)d_in[2];
    const float* W1m  = (const float*)d_in[3];
    const float* b1m  = (const float*)d_in[4];
    const float* W2m  = (const float*)d_in[5];
    const float* b2m  = (const float*)d_in[6];
    const float* W1u  = (const float*)d_in[7];
    const float* b1u  = (const float*)d_in[8];
    const float* W2u  = (const float*)d_in[9];
    const float* b2u  = (const float*)d_in[10];
    const int*   ei   = (const int*)d_in[11];

    const int n_nodes = in_sizes[0] / D_IN;      // 50000
    const int n_edges = in_sizes[11] / 2;        // 1600000

    float* out = (float*)d_out;

    const int NBn = (n_nodes + 255) / 256;       // 196 (<=256 req'd for scan)
    const int NBe = (n_edges + 255) / 256;       // 6250 edge blocks

    // Workspace layout (~45.2 MB):
    //   P1           : n_nodes * D_H    f    (12.8 MB)
    //   P2b          : n_nodes * D_H    u16  (6.4 MB)
    //   edges_sorted : n_edges          ll   (12.8 MB)
    //   deg/offs     : n_nodes          i
    //   bsum/boffs   : 256              i
    //   W1Ep         : 8*64   v2h (2 KB)
    //   tail (ALIASED by lifetime):
    //     rank : n_edges i     (6.4 MB,  live prep -> scatter)
    //     hagg : n_nodes*D_H f (12.8 MB, live gather -> node_upd)
    float*          P1  = (float*)d_ws;
    unsigned short* P2b = (unsigned short*)(P1 + (size_t)n_nodes * D_H);
    long long* edges_sorted = (long long*)(P2b + (size_t)n_nodes * D_H);
    int* deg    = (int*)(edges_sorted + n_edges);
    int* offs   = deg    + n_nodes;
    int* bsum   = offs   + n_nodes;
    int* boffs  = bsum   + 256;
    v2h* W1Ep   = (v2h*)(boffs + 256);
    int* rank   = (int*)(W1Ep + 8 * D_H);
    float* hagg = (float*)rank;                  // alias (disjoint lifetime)

    hipMemsetAsync(deg, 0, (size_t)n_nodes * sizeof(int), stream);

    prep_kernel<<<NBn + NBe + 1, 256, 0, stream>>>(
        x, W1m, b1m, ei, P1, P2b, deg, rank, W1Ep,
        n_nodes, n_edges, NBn, NBe);

    scan_partials_kernel<<<NBn, 256, 0, stream>>>(deg, bsum, n_nodes);
    scan_blockoffs_kernel<<<1, 256, 0, stream>>>(bsum, boffs, NBn);
    scan_final_kernel<<<NBn, 256, 0, stream>>>(deg, boffs, offs, n_nodes);

    scatter_kernel<<<NBe, 256, 0, stream>>>(ei, rank, offs, edges_sorted, n_edges);

    {
        int grid = (n_nodes + 3) / 4;   // 4 nodes/block, 4 waves = comp quarters
        gather_kernel<<<grid, 256, 0, stream>>>(ef, W1Ep, P1, P2b,
                                                deg, offs, edges_sorted, hagg,
                                                n_nodes);
    }
    node_upd_kernel<<<NBn, 256, 0, stream>>>(x, hagg, deg, b2m, W2m,
                                             W1u, b1u, W2u, b2u, out, n_nodes);
}